// Round 20
// baseline (93.420 us; speedup 1.0000x reference)
//
#include <hip/hip_runtime.h>
#include <hip/hip_bf16.h>
#include <stdint.h>

// NMS (YOLO-style) x=(16, 25200, 85) f32 -> out=(16, 300, 6) f32.
// R20: TWO graph nodes. K1 score (R13). K2 fuses select+sort+NMS+output:
// after the register bitonic, per-class wave-greedy NMS (suppression is
// exactly class-local; sequential greedy per class == reference fori_loop)
// runs barrier-free in registers, then in-LDS output assembly. Deletes the
// jacobi kernel, its boundary, and the obox/det/keep0w round-trips.
// All decision floats bit-identical (same exprs, commutative adds).

#define NB 16
#define NA 25200
#define NK 1024
#define ND 300
#define CAP 2048
#define NBIN 4096
#define NCLS 80

// monotone transform: larger float <=> larger uint32
__device__ __forceinline__ uint32_t fkey(float f) {
    uint32_t b = __float_as_uint(f);
    return (b & 0x80000000u) ? ~b : (b | 0x80000000u);
}

__device__ __forceinline__ int score_bin(float s) {
    float f = (s - 0.25f) * (4096.0f / 0.75f);
    int b = (int)f;
    return b > (NBIN - 1) ? (NBIN - 1) : (b < 0 ? 0 : b);
}

__device__ __forceinline__ float key_score(uint32_t u) {
    uint32_t fb = (u & 0x80000000u) ? (u ^ 0x80000000u) : ~u;
    return __uint_as_float(fb);
}

// ---- K1: per-anchor score/class/box + fixed-slot candidate write ----
__global__ void score_kernel(const float* __restrict__ x,
                             float4* __restrict__ boxes,
                             unsigned long long* __restrict__ candw) {
    int b = blockIdx.y;
    int a = blockIdx.x * 16 + (threadIdx.x >> 4);
    int lane = threadIdx.x & 15;
    const float* p = x + (size_t)(b * NA + a) * 85;
    float obj = p[4];
    float best = -1e30f;
    int bi = 0;
#pragma unroll
    for (int r = 0; r < 5; ++r) {
        int j = lane + 16 * r;
        float v = obj * p[5 + j];
        if (v > best) { best = v; bi = j; }  // strict > : first max in-lane
    }
    for (int off = 8; off >= 1; off >>= 1) {
        float ov = __shfl_xor(best, off, 16);
        int   oi = __shfl_xor(bi,   off, 16);
        if (ov > best || (ov == best && oi < bi)) { best = ov; bi = oi; }
    }
    if (lane == 0) {
        float cx = p[0], cy = p[1], w = p[2], h = p[3];
        boxes[b * NA + a] = make_float4(cx - w * 0.5f, cy - h * 0.5f,
                                        cx + w * 0.5f, cy + h * 0.5f);
        unsigned long long key = 0ULL;
        if (best > 0.25f)
            key = ((unsigned long long)fkey(best) << 32) |
                  ((unsigned long long)(unsigned)(NA - 1 - a) << 7) |
                  (unsigned)bi;
        candw[(size_t)b * NA + a] = key;  // 0 = not a candidate
    }
}

// ---- K2: fused hist + threshold + compact + bitonic + per-class greedy
//          NMS + output. One block per batch, 1024 threads, ~52KB LDS. ----
__global__ void __launch_bounds__(1024)
tail_kernel(const unsigned long long* __restrict__ candw,
            const float4* __restrict__ boxes,
            float* __restrict__ out) {
    int b = blockIdx.x;
    int t = threadIdx.x;  // 1024
    int wid = t >> 6, lane = t & 63;
    __shared__ __align__(16) char regionA[NBIN * 4];  // lhist -> oboxS
    __shared__ __align__(16) char regionB[CAP * 8];   // sk -> dboxS
    __shared__ float2 dscl[NK];                       // 8 KiB (score, cls)
    __shared__ unsigned long long cmaskS[NCLS * 16];  // 10 KiB
    __shared__ unsigned long long aliveS[16];
    __shared__ unsigned int wsum[16];
    __shared__ int sB;
    __shared__ unsigned int scnt;
    __shared__ int list[ND];
    __shared__ int totalS;
    unsigned int* lhist = (unsigned int*)regionA;
    float4* oboxS = (float4*)regionA;  // valid after phase A
    unsigned long long* sk = (unsigned long long*)regionB;
    float4* dboxS = (float4*)regionB;  // valid after bitonic

    const ulonglong2* cb2 = (const ulonglong2*)(candw + (size_t)b * NA);

    // --- phase A0: zero + build LDS histogram from candidate slots ---
    ((uint4*)lhist)[t] = make_uint4(0u, 0u, 0u, 0u);
    sk[t] = 0ULL; sk[t + 1024] = 0ULL;
    cmaskS[t] = 0ULL;
    if (t < NCLS * 16 - 1024) cmaskS[1024 + t] = 0ULL;
    if (t == 0) { sB = -1; scnt = 0u; }
    __syncthreads();
    for (int i = t; i < NA / 2; i += 1024) {
        ulonglong2 k2 = cb2[i];
        if (k2.x)
            atomicAdd(&lhist[score_bin(key_score((uint32_t)(k2.x >> 32)))], 1u);
        if (k2.y)
            atomicAdd(&lhist[score_bin(key_score((uint32_t)(k2.y >> 32)))], 1u);
    }
    __syncthreads();

    // --- phase A: suffix scan via wave shfl -> threshold bin B ---
    uint4 hv = ((const uint4*)lhist)[t];  // bins t*4 .. t*4+3
    unsigned int mysum = hv.x + hv.y + hv.z + hv.w;
    unsigned int ssfx = mysum;
#pragma unroll
    for (int off = 1; off < 64; off <<= 1) {
        unsigned int v = __shfl_down(ssfx, off);
        if (lane + off < 64) ssfx += v;
    }
    if (lane == 0) wsum[wid] = ssfx;
    __syncthreads();
    unsigned int tail = 0;
    for (int w2 = wid + 1; w2 < 16; ++w2) tail += wsum[w2];
    unsigned int S_t = ssfx + tail;
    unsigned int Snext = S_t - mysum;
    unsigned int s3 = hv.w + Snext;
    unsigned int s2 = hv.z + s3;
    unsigned int s1 = hv.y + s2;
    unsigned int s0 = hv.x + s1;
    int loc = -1;
    if (s3 >= NK) loc = t * 4 + 3;
    else if (s2 >= NK) loc = t * 4 + 2;
    else if (s1 >= NK) loc = t * 4 + 1;
    else if (s0 >= NK) loc = t * 4 + 0;
#pragma unroll
    for (int off = 32; off >= 1; off >>= 1) {
        int o = __shfl_xor(loc, off);
        loc = o > loc ? o : loc;
    }
    if ((t & 63) == 0) atomicMax(&sB, loc);
    __syncthreads();
    int B = sB < 0 ? 0 : sB;

    // --- phase B: filter slots by bin >= B into sk ---
    for (int i = t; i < NA / 2; i += 1024) {
        ulonglong2 k2 = cb2[i];
        unsigned long long ke[2] = {k2.x, k2.y};
#pragma unroll
        for (int e = 0; e < 2; ++e) {
            unsigned long long k = ke[e];
            bool q = (k != 0ULL) &&
                     (score_bin(key_score((uint32_t)(k >> 32))) >= B);
            unsigned long long m = __ballot(q);
            if (q) {
                int nbelow = __popcll(m & ((1ULL << lane) - 1));
                int leader = __ffsll((long long)m) - 1;
                unsigned int base = 0;
                if (lane == leader)
                    base = atomicAdd(&scnt, (unsigned int)__popcll(m));
                base = __shfl(base, leader);
                unsigned int pos = base + nbelow;
                if (pos < CAP) sk[pos] = k;
            }
        }
    }
    __syncthreads();

    // --- phase C: register bitonic sort (descending) ---
    const int e1 = t, e2 = t + 1024;
    unsigned long long v1 = sk[e1];
    unsigned long long v2 = sk[e2];
    __syncthreads();
    for (int k = 2; k <= CAP; k <<= 1) {
        for (int j = k >> 1; j > 0; j >>= 1) {
            if (j >= 1024) {
                unsigned long long lo = v1 < v2 ? v1 : v2;
                unsigned long long hi = v1 < v2 ? v2 : v1;
                v1 = hi; v2 = lo;
            } else if (j >= 64) {
                sk[e1] = v1; sk[e2] = v2;
                __syncthreads();
                unsigned long long p1 = sk[e1 ^ j], p2 = sk[e2 ^ j];
                __syncthreads();
                {
                    bool takeMax = (((e1 & j) == 0) == ((e1 & k) == 0));
                    bool g = p1 > v1;
                    v1 = (takeMax == g) ? p1 : v1;
                }
                {
                    bool takeMax = (((e2 & j) == 0) == ((e2 & k) == 0));
                    bool g = p2 > v2;
                    v2 = (takeMax == g) ? p2 : v2;
                }
            } else {
                {
                    unsigned long long p1 =
                        (unsigned long long)__shfl_xor((long long)v1, j);
                    bool takeMax = (((e1 & j) == 0) == ((e1 & k) == 0));
                    bool g = p1 > v1;
                    v1 = (takeMax == g) ? p1 : v1;
                }
                {
                    unsigned long long p2 =
                        (unsigned long long)__shfl_xor((long long)v2, j);
                    bool takeMax = (((e2 & j) == 0) == ((e2 & k) == 0));
                    bool g = p2 > v2;
                    v2 = (takeMax == g) ? p2 : v2;
                }
            }
        }
    }
    __syncthreads();  // sk (regionB) now dead -> reuse as dboxS

    // --- phase D: decode rank-t key; gather; stage in LDS; class buckets ---
    unsigned long long key = v1;  // rank t
    uint32_t u = (uint32_t)(key >> 32);
    uint32_t low = (uint32_t)key;
    int a = (u == 0) ? 0 : (int)(NA - 1 - (low >> 7));
    int ci = (u == 0) ? 0 : (int)(low & 0x7Fu);
    float s = key_score(u);  // NaN for pad (u==0)
    float4 bx = boxes[b * NA + a];
    float c = (float)ci;
    float off = c * 7680.0f;
    float4 ob = make_float4(bx.x + off, bx.y + off, bx.z + off, bx.w + off);
    oboxS[t] = ob;   // regionA (lhist dead since phase A)
    dboxS[t] = bx;   // regionB
    dscl[t] = make_float2(s, c);
    bool keep0 = s > 0.25f;  // false for pad (NaN)
    unsigned long long bal = __ballot(keep0);
    if (lane == 0) aliveS[wid] = bal;
    atomicOr(&cmaskS[ci * 16 + wid], 1ULL << lane);
    __syncthreads();

    // --- phase E: per-class wave-greedy NMS (barrier-free) ---
    // Sequential greedy within each class == reference fori_loop restricted
    // to the class (cross-class IoU exactly 0). Wave w owns classes 5w..5w+4.
    for (int kc = 0; kc < 5; ++kc) {
        int ccls = wid * 5 + kc;
        // enumerate member ranks ascending; lane L = L-th member
        int myRank = -1;
        int cnt = 0;
        for (int wo = 0; wo < 16; ++wo) {
            unsigned long long bits = cmaskS[ccls * 16 + wo];
            int pc = __popcll(bits);
            if (lane >= cnt && lane < cnt + pc) {
                unsigned long long b2 = bits;
                for (int z = lane - cnt; z > 0; --z) b2 &= b2 - 1;
                myRank = wo * 64 + __ffsll((long long)b2) - 1;
            }
            cnt += pc;
        }
        int m = cnt;  // wave-uniform
        if (m <= 1) continue;
        if (m <= 64) {
            float4 mb = make_float4(0.f, 0.f, 0.f, 0.f);
            bool alive0 = false;
            if (myRank >= 0) {
                alive0 = (aliveS[myRank >> 6] >> (myRank & 63)) & 1ULL;
                mb = oboxS[myRank];
            }
            bool alive = alive0;
            float marea = (mb.z - mb.x) * (mb.w - mb.y);
            for (int j = 0; j < m - 1; ++j) {
                int aj = __shfl((int)alive, j);
                float bx1 = __shfl(mb.x, j);
                float by1 = __shfl(mb.y, j);
                float bx2 = __shfl(mb.z, j);
                float by2 = __shfl(mb.w, j);
                float barea = __shfl(marea, j);
                if (aj && alive && lane > j && myRank >= 0) {
                    float ix1 = fmaxf(mb.x, bx1), iy1 = fmaxf(mb.y, by1);
                    float ix2 = fminf(mb.z, bx2), iy2 = fminf(mb.w, by2);
                    float iw = fmaxf(ix2 - ix1, 0.0f);
                    float ih = fmaxf(iy2 - iy1, 0.0f);
                    float inter = iw * ih;
                    float uni = marea + barea - inter;  // commutative == ref
                    float iou = inter / (uni + 1e-9f);
                    if (iou > 0.45f) alive = false;
                }
            }
            if (alive0 && !alive)
                atomicAnd(&aliveS[myRank >> 6], ~(1ULL << (myRank & 63)));
        } else if (lane == 0) {
            // generic fallback (not expected on this data): serial greedy
            for (int ra = 0; ra < NK; ++ra) {
                if (!((cmaskS[ccls * 16 + (ra >> 6)] >> (ra & 63)) & 1ULL))
                    continue;
                if (!((aliveS[ra >> 6] >> (ra & 63)) & 1ULL)) continue;
                float4 A = oboxS[ra];
                float aarea = (A.z - A.x) * (A.w - A.y);
                for (int rb2 = ra + 1; rb2 < NK; ++rb2) {
                    if (!((cmaskS[ccls * 16 + (rb2 >> 6)] >> (rb2 & 63)) &
                          1ULL))
                        continue;
                    if (!((aliveS[rb2 >> 6] >> (rb2 & 63)) & 1ULL)) continue;
                    float4 Bx = oboxS[rb2];
                    float barea = (Bx.z - Bx.x) * (Bx.w - Bx.y);
                    float ix1 = fmaxf(Bx.x, A.x), iy1 = fmaxf(Bx.y, A.y);
                    float ix2 = fminf(Bx.z, A.z), iy2 = fminf(Bx.w, A.w);
                    float iw = fmaxf(ix2 - ix1, 0.0f);
                    float ih = fmaxf(iy2 - iy1, 0.0f);
                    float inter = iw * ih;
                    float uni = barea + aarea - inter;
                    float iou = inter / (uni + 1e-9f);
                    if (iou > 0.45f)
                        atomicAnd(&aliveS[rb2 >> 6],
                                  ~(1ULL << (rb2 & 63)));
                }
            }
        }
    }
    __syncthreads();

    // --- phase F: ordered kept list + output ---
    if (t < 64) {
        unsigned long long av = (lane < 16) ? aliveS[lane] : 0ULL;
        int cnt2 = (lane < 16) ? __popcll(av) : 0;
        int pre = cnt2;
        for (int off2 = 1; off2 < 64; off2 <<= 1) {
            int v = __shfl_up(pre, off2);
            if (lane >= off2) pre += v;
        }
        int total = __shfl(pre, 63);
        int base = pre - cnt2;
        if (lane == 0) totalS = total;
        if (lane < 16) {
            unsigned long long m = av;
            int pos = base;
            while (m && pos < ND) {
                int bit = __ffsll((long long)m) - 1;
                list[pos++] = lane * 64 + bit;
                m &= m - 1;
            }
        }
    }
    __syncthreads();
    if (t < ND) {
        float vals[6] = {0, 0, 0, 0, 0, 0};
        if (t < totalS) {
            int i = list[t];
            float4 db = dboxS[i];
            float2 sl = dscl[i];
            vals[0] = db.x; vals[1] = db.y; vals[2] = db.z; vals[3] = db.w;
            vals[4] = sl.x; vals[5] = sl.y;
        }
        float* o = out + (size_t)(b * ND + t) * 6;
#pragma unroll
        for (int c2 = 0; c2 < 6; ++c2) o[c2] = vals[c2];
    }
}

extern "C" void kernel_launch(void* const* d_in, const int* in_sizes, int n_in,
                              void* d_out, int out_size, void* d_ws, size_t ws_size,
                              hipStream_t stream) {
    const float* x = (const float*)d_in[0];
    float* out = (float*)d_out;

    char* ws = (char*)d_ws;
    size_t off = 0;
    auto alloc = [&](size_t bytes) {
        void* p = ws + off;
        off += (bytes + 255) & ~(size_t)255;
        return p;
    };
    float4* boxes = (float4*)alloc((size_t)NB * NA * sizeof(float4));
    unsigned long long* candw =
        (unsigned long long*)alloc((size_t)NB * NA * sizeof(unsigned long long));
    (void)ws_size;

    score_kernel<<<dim3(NA / 16, NB), 256, 0, stream>>>(x, boxes, candw);
    tail_kernel<<<NB, 1024, 0, stream>>>(candw, boxes, out);
}

// Round 21
// 82.939 us; speedup vs baseline: 1.1264x; 1.1264x over previous
//
#include <hip/hip_runtime.h>
#include <hip/hip_bf16.h>
#include <stdint.h>

// NMS (YOLO-style) x=(16, 25200, 85) f32 -> out=(16, 300, 6) f32.
// R21 = R13 RESTORED (best measured config: 83.0us).
// 3 graph nodes: score -> select_sort -> fused mask+jacobi+output.
// Ledger (R15/R16/R18 diagnostics): score ~24us (HBM floor for the 137MB
// input read), select_sort ~28us + nms ~26us (16-block latency-bound tail;
// seven restructurings were null or regressions), overhead ~5us.
// All decisions bit-exact vs the JAX reference (absmax 0.0 every round).

#define NB 16
#define NA 25200
#define NK 1024
#define ND 300
#define CAP 2048
#define NBIN 4096
#define NCLS 80

// monotone transform: larger float <=> larger uint32
__device__ __forceinline__ uint32_t fkey(float f) {
    uint32_t b = __float_as_uint(f);
    return (b & 0x80000000u) ? ~b : (b | 0x80000000u);
}

// linear bin over (0.25, 1); applied to the decoded score float (bit-equal
// to the original best) -> identical bin everywhere.
__device__ __forceinline__ int score_bin(float s) {
    float f = (s - 0.25f) * (4096.0f / 0.75f);
    int b = (int)f;
    return b > (NBIN - 1) ? (NBIN - 1) : (b < 0 ? 0 : b);
}

// key = fkey(s)<<32 | (NA-1-a)<<7 | cls : descending key order ==
// (score desc, anchor idx asc); cls rides in bits [0,7).
__device__ __forceinline__ float key_score(uint32_t u) {
    uint32_t fb = (u & 0x80000000u) ? (u ^ 0x80000000u) : ~u;
    return __uint_as_float(fb);
}

// ---- K1: per-anchor score/class/box + fixed-slot candidate write ----
__global__ void score_kernel(const float* __restrict__ x,
                             float4* __restrict__ boxes,
                             unsigned long long* __restrict__ candw) {
    int b = blockIdx.y;
    int a = blockIdx.x * 16 + (threadIdx.x >> 4);
    int lane = threadIdx.x & 15;
    const float* p = x + (size_t)(b * NA + a) * 85;
    float obj = p[4];
    float best = -1e30f;
    int bi = 0;
#pragma unroll
    for (int r = 0; r < 5; ++r) {
        int j = lane + 16 * r;
        float v = obj * p[5 + j];
        if (v > best) { best = v; bi = j; }  // strict > : first max in-lane
    }
    // reduce across 16-lane group; tie -> lower class index (jnp.argmax)
    for (int off = 8; off >= 1; off >>= 1) {
        float ov = __shfl_xor(best, off, 16);
        int   oi = __shfl_xor(bi,   off, 16);
        if (ov > best || (ov == best && oi < bi)) { best = ov; bi = oi; }
    }
    if (lane == 0) {
        float cx = p[0], cy = p[1], w = p[2], h = p[3];
        boxes[b * NA + a] = make_float4(cx - w * 0.5f, cy - h * 0.5f,
                                        cx + w * 0.5f, cy + h * 0.5f);
        unsigned long long key = 0ULL;
        if (best > 0.25f)
            key = ((unsigned long long)fkey(best) << 32) |
                  ((unsigned long long)(unsigned)(NA - 1 - a) << 7) |
                  (unsigned)bi;
        candw[(size_t)b * NA + a] = key;  // 0 = not a candidate
    }
}

// -- K2: hist(from candw) + threshold + compact + bitonic sort + gather --
__global__ void __launch_bounds__(1024)
select_sort_kernel(const unsigned long long* __restrict__ candw,
                   const float4* __restrict__ boxes,
                   float4* __restrict__ obox,
                   float* __restrict__ det,
                   unsigned long long* __restrict__ keep0w) {
    int b = blockIdx.x;
    int t = threadIdx.x;  // 1024
    int wid = t >> 6, lane = t & 63;
    __shared__ unsigned int lhist[NBIN];    // 16 KiB
    __shared__ unsigned long long sk[CAP];  // 16 KiB
    __shared__ unsigned int wsum[16];
    __shared__ int sB;
    __shared__ unsigned int scnt;

    const ulonglong2* cb2 = (const ulonglong2*)(candw + (size_t)b * NA);

    // --- phase A0: zero + build LDS histogram from candidate slots ---
    ((uint4*)lhist)[t] = make_uint4(0u, 0u, 0u, 0u);
    sk[t] = 0ULL; sk[t + 1024] = 0ULL;
    if (t == 0) { sB = -1; scnt = 0u; }
    __syncthreads();
    for (int i = t; i < NA / 2; i += 1024) {
        ulonglong2 k2 = cb2[i];
        if (k2.x)
            atomicAdd(&lhist[score_bin(key_score((uint32_t)(k2.x >> 32)))], 1u);
        if (k2.y)
            atomicAdd(&lhist[score_bin(key_score((uint32_t)(k2.y >> 32)))], 1u);
    }
    __syncthreads();

    // --- phase A: suffix scan via wave shfl ---
    uint4 hv = ((const uint4*)lhist)[t];  // bins t*4 .. t*4+3
    unsigned int mysum = hv.x + hv.y + hv.z + hv.w;
    unsigned int ssfx = mysum;
#pragma unroll
    for (int off = 1; off < 64; off <<= 1) {
        unsigned int v = __shfl_down(ssfx, off);
        if (lane + off < 64) ssfx += v;
    }
    if (lane == 0) wsum[wid] = ssfx;
    __syncthreads();
    unsigned int tail = 0;
    for (int w2 = wid + 1; w2 < 16; ++w2) tail += wsum[w2];
    unsigned int S_t = ssfx + tail;
    unsigned int Snext = S_t - mysum;
    unsigned int s3 = hv.w + Snext;
    unsigned int s2 = hv.z + s3;
    unsigned int s1 = hv.y + s2;
    unsigned int s0 = hv.x + s1;
    int loc = -1;
    if (s3 >= NK) loc = t * 4 + 3;
    else if (s2 >= NK) loc = t * 4 + 2;
    else if (s1 >= NK) loc = t * 4 + 1;
    else if (s0 >= NK) loc = t * 4 + 0;
#pragma unroll
    for (int off = 32; off >= 1; off >>= 1) {
        int o = __shfl_xor(loc, off);
        loc = o > loc ? o : loc;
    }
    if ((t & 63) == 0) atomicMax(&sB, loc);
    __syncthreads();
    int B = sB < 0 ? 0 : sB;

    // --- phase B: filter slots by bin >= B into LDS ---
    for (int i = t; i < NA / 2; i += 1024) {
        ulonglong2 k2 = cb2[i];
        unsigned long long ke[2] = {k2.x, k2.y};
#pragma unroll
        for (int e = 0; e < 2; ++e) {
            unsigned long long k = ke[e];
            bool q = (k != 0ULL) &&
                     (score_bin(key_score((uint32_t)(k >> 32))) >= B);
            unsigned long long m = __ballot(q);
            if (q) {
                int nbelow = __popcll(m & ((1ULL << lane) - 1));
                int leader = __ffsll((long long)m) - 1;
                unsigned int base = 0;
                if (lane == leader)
                    base = atomicAdd(&scnt, (unsigned int)__popcll(m));
                base = __shfl(base, leader);
                unsigned int pos = base + nbelow;
                if (pos < CAP) sk[pos] = k;
            }
        }
    }
    __syncthreads();

    // --- phase C: register bitonic sort (descending) ---
    const int e1 = t, e2 = t + 1024;
    unsigned long long v1 = sk[e1];
    unsigned long long v2 = sk[e2];
    __syncthreads();
    for (int k = 2; k <= CAP; k <<= 1) {
        for (int j = k >> 1; j > 0; j >>= 1) {
            if (j >= 1024) {
                unsigned long long lo = v1 < v2 ? v1 : v2;
                unsigned long long hi = v1 < v2 ? v2 : v1;
                v1 = hi; v2 = lo;
            } else if (j >= 64) {
                sk[e1] = v1; sk[e2] = v2;
                __syncthreads();
                unsigned long long p1 = sk[e1 ^ j], p2 = sk[e2 ^ j];
                __syncthreads();
                {
                    bool takeMax = (((e1 & j) == 0) == ((e1 & k) == 0));
                    bool g = p1 > v1;
                    v1 = (takeMax == g) ? p1 : v1;
                }
                {
                    bool takeMax = (((e2 & j) == 0) == ((e2 & k) == 0));
                    bool g = p2 > v2;
                    v2 = (takeMax == g) ? p2 : v2;
                }
            } else {
                {
                    unsigned long long p1 =
                        (unsigned long long)__shfl_xor((long long)v1, j);
                    bool takeMax = (((e1 & j) == 0) == ((e1 & k) == 0));
                    bool g = p1 > v1;
                    v1 = (takeMax == g) ? p1 : v1;
                }
                {
                    unsigned long long p2 =
                        (unsigned long long)__shfl_xor((long long)v2, j);
                    bool takeMax = (((e2 & j) == 0) == ((e2 & k) == 0));
                    bool g = p2 > v2;
                    v2 = (takeMax == g) ? p2 : v2;
                }
            }
        }
    }
    // thread t holds rank-t key (ranks 0..1023) in v1
    unsigned long long key = v1;
    uint32_t u = (uint32_t)(key >> 32);
    uint32_t low = (uint32_t)key;
    int a = (u == 0) ? 0 : (int)(NA - 1 - (low >> 7));
    int cls = (u == 0) ? 0 : (int)(low & 0x7Fu);
    float s = key_score(u);  // NaN for pad (u==0)
    float4 bx = boxes[b * NA + a];
    float c = (float)cls;
    float off = c * 7680.0f;
    obox[b * NK + t] =
        make_float4(bx.x + off, bx.y + off, bx.z + off, bx.w + off);
    float* dr = det + (size_t)(b * NK + t) * 8;
    dr[0] = bx.x; dr[1] = bx.y; dr[2] = bx.z; dr[3] = bx.w;
    dr[4] = s; dr[5] = c;
    bool keep0 = s > 0.25f;  // false for pad (NaN)
    unsigned long long bal = __ballot(keep0);
    if ((t & 63) == 0) keep0w[b * 16 + (t >> 6)] = bal;
}

// -- K3: fused supby-row (class buckets) + Jacobi NMS + output --
// Row bits match the full mask for every alive-relevant pair: cross-class
// IoU is exactly 0 (offset gap >= 7678 > box span); same-class uses
// identical float expressions; pad bits are masked by alive=0.
__global__ void __launch_bounds__(1024)
nms_out_kernel(const float4* __restrict__ obox,
               const float* __restrict__ det,
               const unsigned long long* __restrict__ keep0w,
               float* __restrict__ out) {
    int b = blockIdx.x;
    int t = threadIdx.x;  // 1024; thread t owns row t
    int wid = t >> 6, lane = t & 63;
    __shared__ float4 oboxS[NK];                      // 16 KiB
    __shared__ unsigned long long cmaskS[NCLS * 16];  // 10 KiB
    __shared__ unsigned long long aliveS[16];
    __shared__ int changedS;
    __shared__ int list[ND];
    __shared__ int totalS;

    float4 ob = obox[b * NK + t];
    const float* dr = det + (size_t)(b * NK + t) * 8;
    int ci = (int)dr[5];
    oboxS[t] = ob;
    cmaskS[t] = 0ULL;
    if (t < NCLS * 16 - 1024) cmaskS[1024 + t] = 0ULL;
    bool keep0 = (keep0w[b * 16 + wid] >> lane) & 1ULL;
    if (t < 16) aliveS[t] = keep0w[b * 16 + t];
    __syncthreads();
    atomicOr(&cmaskS[ci * 16 + wid], 1ULL << lane);
    __syncthreads();

    // --- supby row via class bucket ---
    unsigned long long row[16];
#pragma unroll
    for (int w = 0; w < 16; ++w) row[w] = 0ULL;
    float ra = (ob.z - ob.x) * (ob.w - ob.y);
    for (int w = 0; w <= wid; ++w) {
        unsigned long long bits = cmaskS[ci * 16 + w];
        if (w == wid)
            bits &= (lane == 0) ? 0ULL : ((1ULL << lane) - 1ULL);  // j < t
        unsigned long long rbits = 0ULL;
        while (bits) {
            int bit = __ffsll((long long)bits) - 1;
            bits &= bits - 1;
            float4 o = oboxS[w * 64 + bit];
            float carea = (o.z - o.x) * (o.w - o.y);
            float ix1 = fmaxf(ob.x, o.x), iy1 = fmaxf(ob.y, o.y);
            float ix2 = fminf(ob.z, o.z), iy2 = fminf(ob.w, o.w);
            float iw = fmaxf(ix2 - ix1, 0.0f), ih = fmaxf(iy2 - iy1, 0.0f);
            float inter = iw * ih;
            float uni = ra + carea - inter;
            float iou = inter / (uni + 1e-9f);
            if (iou > 0.45f) rbits |= (1ULL << bit);
        }
        row[w] = rbits;
    }
    __syncthreads();

    // --- Jacobi fixed-point NMS ---
    for (int it = 0; it < NK; ++it) {
        if (t == 0) changedS = 0;
        unsigned long long aw[16];
#pragma unroll
        for (int w = 0; w < 16; ++w) aw[w] = aliveS[w];  // snapshot
        __syncthreads();
        unsigned long long sup = 0;
#pragma unroll
        for (int w = 0; w < 16; ++w) sup |= aw[w] & row[w];
        bool newalive = keep0 && (sup == 0);
        unsigned long long nb = __ballot(newalive);
        if (lane == 0) {
            if (nb != aw[wid]) { atomicOr(&changedS, 1); aliveS[wid] = nb; }
        }
        __syncthreads();
        if (!changedS) break;
    }

    // --- ordered kept list + output ---
    if (t < 64) {
        unsigned long long av = (lane < 16) ? aliveS[lane] : 0ULL;
        int cnt2 = (lane < 16) ? __popcll(av) : 0;
        int pre = cnt2;
        for (int off = 1; off < 64; off <<= 1) {
            int v = __shfl_up(pre, off);
            if (lane >= off) pre += v;
        }
        int total = __shfl(pre, 63);
        int base = pre - cnt2;
        if (lane == 0) totalS = total;
        if (lane < 16) {
            unsigned long long m = av;
            int pos = base;
            while (m && pos < ND) {
                int bit = __ffsll((long long)m) - 1;
                list[pos++] = lane * 64 + bit;
                m &= m - 1;
            }
        }
    }
    __syncthreads();
    if (t < ND) {
        float vals[6] = {0, 0, 0, 0, 0, 0};
        if (t < totalS) {
            const float* dr2 = det + (size_t)(b * NK + list[t]) * 8;
#pragma unroll
            for (int c = 0; c < 6; ++c) vals[c] = dr2[c];
        }
        float* o = out + (size_t)(b * ND + t) * 6;
#pragma unroll
        for (int c = 0; c < 6; ++c) o[c] = vals[c];
    }
}

extern "C" void kernel_launch(void* const* d_in, const int* in_sizes, int n_in,
                              void* d_out, int out_size, void* d_ws, size_t ws_size,
                              hipStream_t stream) {
    const float* x = (const float*)d_in[0];
    float* out = (float*)d_out;

    char* ws = (char*)d_ws;
    size_t off = 0;
    auto alloc = [&](size_t bytes) {
        void* p = ws + off;
        off += (bytes + 255) & ~(size_t)255;
        return p;
    };
    float4* boxes = (float4*)alloc((size_t)NB * NA * sizeof(float4));
    unsigned long long* candw =
        (unsigned long long*)alloc((size_t)NB * NA * sizeof(unsigned long long));
    float4* obox = (float4*)alloc((size_t)NB * NK * sizeof(float4));
    float* det = (float*)alloc((size_t)NB * NK * 8 * sizeof(float));
    unsigned long long* keep0w =
        (unsigned long long*)alloc((size_t)NB * 16 * sizeof(unsigned long long));
    (void)ws_size;

    score_kernel<<<dim3(NA / 16, NB), 256, 0, stream>>>(x, boxes, candw);
    select_sort_kernel<<<NB, 1024, 0, stream>>>(candw, boxes, obox, det,
                                                keep0w);
    nms_out_kernel<<<NB, 1024, 0, stream>>>(obox, det, keep0w, out);
}